// Round 2
// baseline (291.801 us; speedup 1.0000x reference)
//
#include <hip/hip_runtime.h>
#include <hip/hip_bf16.h>
#include <stdint.h>

#define NUM_MODALS 4
#define SHARED_IDX 3

typedef __attribute__((ext_vector_type(8))) short bf16x8;
typedef __attribute__((ext_vector_type(4))) float floatx4;

__device__ __forceinline__ unsigned short f2bf(float f) {
  unsigned int u = __float_as_uint(f);
  u += 0x7fffu + ((u >> 16) & 1u);   // round-to-nearest-even
  return (unsigned short)(u >> 16);
}

// ---------------- W_eff precompute ----------------
// W_eff[m][o][c] = Wp[o][c] + sum_r Bw[3][o][r]*A[3][r][c] + sum_r Bw[m][o][r]*A[m][r][c]
__global__ void weff_kernel(const float* __restrict__ Wp,
                            const float* __restrict__ A,
                            const float* __restrict__ Bw,
                            unsigned short* __restrict__ Weff) {
  const int o = blockIdx.x;
  const int m = blockIdx.y;
  __shared__ float bsh[32];
  const int t = threadIdx.x;
  if (t < 16)      bsh[t] = Bw[(SHARED_IDX * 768 + o) * 16 + t];
  else if (t < 32) bsh[t] = Bw[(m * 768 + o) * 16 + (t - 16)];
  __syncthreads();
  for (int c = t; c < 768; c += 256) {
    float acc = Wp[o * 768 + c];
#pragma unroll
    for (int r = 0; r < 16; ++r) {
      acc += bsh[r]      * A[(SHARED_IDX * 16 + r) * 768 + c];
      acc += bsh[16 + r] * A[(m * 16 + r) * 768 + c];
    }
    Weff[((size_t)m * 768 + o) * 768 + c] = f2bf(acc);
  }
}

// ---------------- X fp32 -> bf16 convert (memory-bound) ----------------
__global__ __launch_bounds__(256) void xconv_kernel(const float* __restrict__ X,
                                                    unsigned short* __restrict__ Xb,
                                                    int n4) {
  int idx = blockIdx.x * 256 + threadIdx.x;
  const int stride = gridDim.x * 256;
  for (; idx < n4; idx += stride) {
    const float4 v = *(const float4*)(X + (size_t)idx * 4);
    ushort4 h;
    h.x = f2bf(v.x); h.y = f2bf(v.y); h.z = f2bf(v.z); h.w = f2bf(v.w);
    *(ushort4*)(Xb + (size_t)idx * 4) = h;
  }
}

// ---------------- main GEMM: out[m] = Xb[m] (8192x768 bf16) * Weff[m]^T + bp ----------------
// 128x128 tile, BK=64, 4 waves x (64x64 via 4x4 16x16x32 MFMA frags).
// Both tiles staged with global_load_lds width-16; LDS layout XOR-swizzled:
// row r, col-block kblk (8 bf16) lives at slot kblk ^ (r & 7).
__global__ __launch_bounds__(256) void lora_gemm_bf16(
    const unsigned short* __restrict__ Xb,
    const unsigned short* __restrict__ Weff,
    const float* __restrict__ bp,
    float* __restrict__ out) {
  const int m = blockIdx.z;
  const int row_base = blockIdx.y * 128;
  const int col_base = blockIdx.x * 128;

  __shared__ alignas(16) unsigned short As[128 * 64];
  __shared__ alignas(16) unsigned short Ws[128 * 64];

  const int tid  = threadIdx.x;
  const int wave = tid >> 6;
  const int lane = tid & 63;
  const int ln = lane & 15;
  const int qd = lane >> 4;
  const int wm = wave & 1;
  const int wn = wave >> 1;

  const unsigned short* Xm = Xb   + (size_t)m * 8192 * 768;
  const unsigned short* Wm = Weff + (size_t)m * 768 * 768;

  floatx4 acc[4][4];
#pragma unroll
  for (int i = 0; i < 4; ++i)
#pragma unroll
    for (int j = 0; j < 4; ++j)
      acc[i][j] = (floatx4)(0.0f);

  // staging geometry (per global_load_lds issue: 64 lanes x 16 B = 8 rows x 128 B)
  const int sr = lane >> 3;          // row-in-8 for this lane
  const int ss = lane & 7;           // LDS slot (col-block) this lane fills
  for (int kt = 0; kt < 12; ++kt) {
    const int k0 = kt * 64;

#pragma unroll
    for (int p = 0; p < 4; ++p) {
      const int r = wave * 32 + p * 8 + sr;
      const int g = ss ^ (r & 7);    // global col-block that belongs in slot ss
      const unsigned short* srcA = Xm + (size_t)(row_base + r) * 768 + k0 + g * 8;
      __builtin_amdgcn_global_load_lds(
          (const __attribute__((address_space(1))) void*)srcA,
          (__attribute__((address_space(3))) void*)&As[(wave * 32 + p * 8) * 64],
          16, 0, 0);
      const unsigned short* srcW = Wm + (size_t)(col_base + r) * 768 + k0 + g * 8;
      __builtin_amdgcn_global_load_lds(
          (const __attribute__((address_space(1))) void*)srcW,
          (__attribute__((address_space(3))) void*)&Ws[(wave * 32 + p * 8) * 64],
          16, 0, 0);
    }
    __syncthreads();

#pragma unroll
    for (int kk = 0; kk < 64; kk += 32) {
      const int kblk = (kk >> 3) + qd;           // 0..7
      const int slot = (kblk ^ (ln & 7)) * 8;    // row&7 == ln&7 for all frag rows
      bf16x8 a[4], b[4];
#pragma unroll
      for (int i = 0; i < 4; ++i)
        a[i] = *(const bf16x8*)(&As[(wm * 64 + i * 16 + ln) * 64 + slot]);
#pragma unroll
      for (int j = 0; j < 4; ++j)
        b[j] = *(const bf16x8*)(&Ws[(wn * 64 + j * 16 + ln) * 64 + slot]);
#pragma unroll
      for (int i = 0; i < 4; ++i)
#pragma unroll
        for (int j = 0; j < 4; ++j)
          acc[i][j] = __builtin_amdgcn_mfma_f32_16x16x32_bf16(a[i], b[j], acc[i][j], 0, 0, 0);
    }
    __syncthreads();
  }

  float* Om = out + (size_t)m * 8192 * 768;
#pragma unroll
  for (int j = 0; j < 4; ++j) {
    const int o = col_base + wn * 64 + j * 16 + ln;
    const float bias = bp[o];
#pragma unroll
    for (int i = 0; i < 4; ++i) {
      const int R = row_base + wm * 64 + i * 16 + qd * 4;
      float* dst = Om + (size_t)R * 768 + o;
#pragma unroll
      for (int v = 0; v < 4; ++v)
        dst[(size_t)v * 768] = acc[i][j][v] + bias;
    }
  }
}

// ---------------- fallback GEMM (fp32 X staging, from round 1) ----------------
__global__ __launch_bounds__(256) void lora_gemm_fp32x(
    const float* __restrict__ X,
    const unsigned short* __restrict__ Weff,
    const float* __restrict__ bp,
    float* __restrict__ out) {
  const int m = blockIdx.z;
  const int row_base = blockIdx.y * 128;
  const int col_base = blockIdx.x * 128;
  __shared__ alignas(16) unsigned short As[128 * 64];
  __shared__ alignas(16) unsigned short Ws[128 * 64];
  const int tid  = threadIdx.x;
  const int wave = tid >> 6;
  const int lane = tid & 63;
  const int ln = lane & 15;
  const int qd = lane >> 4;
  const int wm = wave & 1;
  const int wn = wave >> 1;
  const float*          Xm = X    + (size_t)m * 8192 * 768;
  const unsigned short* Wm = Weff + (size_t)m * 768 * 768;
  floatx4 acc[4][4];
#pragma unroll
  for (int i = 0; i < 4; ++i)
#pragma unroll
    for (int j = 0; j < 4; ++j)
      acc[i][j] = (floatx4)(0.0f);
  const int xr = tid >> 4;
  const int xc = (tid & 15) * 4;
  for (int kt = 0; kt < 12; ++kt) {
    const int k0 = kt * 64;
#pragma unroll
    for (int p = 0; p < 8; ++p) {
      const int r = xr + p * 16;
      const float4 v = *(const float4*)(Xm + (size_t)(row_base + r) * 768 + k0 + xc);
      ushort4 h;
      h.x = f2bf(v.x); h.y = f2bf(v.y); h.z = f2bf(v.z); h.w = f2bf(v.w);
      *(ushort4*)(&As[r * 64 + xc]) = h;
    }
#pragma unroll
    for (int p = 0; p < 4; ++p) {
      const unsigned short* src = Wm + (size_t)(col_base + wave * 32 + p * 8 + (lane >> 3)) * 768 + k0 + (lane & 7) * 8;
      __builtin_amdgcn_global_load_lds(
          (const __attribute__((address_space(1))) void*)src,
          (__attribute__((address_space(3))) void*)&Ws[(wave * 32 + p * 8) * 64],
          16, 0, 0);
    }
    __syncthreads();
#pragma unroll
    for (int kk = 0; kk < 64; kk += 32) {
      bf16x8 a[4], b[4];
#pragma unroll
      for (int i = 0; i < 4; ++i)
        a[i] = *(const bf16x8*)(&As[(wm * 64 + i * 16 + ln) * 64 + kk + qd * 8]);
#pragma unroll
      for (int j = 0; j < 4; ++j)
        b[j] = *(const bf16x8*)(&Ws[(wn * 64 + j * 16 + ln) * 64 + kk + qd * 8]);
#pragma unroll
      for (int i = 0; i < 4; ++i)
#pragma unroll
        for (int j = 0; j < 4; ++j)
          acc[i][j] = __builtin_amdgcn_mfma_f32_16x16x32_bf16(a[i], b[j], acc[i][j], 0, 0, 0);
    }
    __syncthreads();
  }
  float* Om = out + (size_t)m * 8192 * 768;
#pragma unroll
  for (int j = 0; j < 4; ++j) {
    const int o = col_base + wn * 64 + j * 16 + ln;
    const float bias = bp[o];
#pragma unroll
    for (int i = 0; i < 4; ++i) {
      const int R = row_base + wm * 64 + i * 16 + qd * 4;
      float* dst = Om + (size_t)R * 768 + o;
#pragma unroll
      for (int v = 0; v < 4; ++v)
        dst[(size_t)v * 768] = acc[i][j][v] + bias;
    }
  }
}

extern "C" void kernel_launch(void* const* d_in, const int* in_sizes, int n_in,
                              void* d_out, int out_size, void* d_ws, size_t ws_size,
                              hipStream_t stream) {
  const float* x  = (const float*)d_in[0];   // [32, 1024, 768]
  const float* Wp = (const float*)d_in[1];   // [768, 768]
  const float* bp = (const float*)d_in[2];   // [768]
  const float* A  = (const float*)d_in[3];   // [4, 16, 768]
  const float* Bw = (const float*)d_in[4];   // [4, 768, 16]
  float* out = (float*)d_out;                // [32, 1024, 768]

  const size_t weff_bytes = (size_t)NUM_MODALS * 768 * 768 * 2;      // 4.5 MB
  const size_t xb_bytes   = (size_t)NUM_MODALS * 8192 * 768 * 2;     // 50.3 MB

  unsigned short* Weff = (unsigned short*)d_ws;
  weff_kernel<<<dim3(768, 4), 256, 0, stream>>>(Wp, A, Bw, Weff);

  if (ws_size >= weff_bytes + xb_bytes) {
    unsigned short* Xb = (unsigned short*)((char*)d_ws + weff_bytes);
    const int n4 = NUM_MODALS * 8192 * 768 / 4;  // 6,291,456 float4 groups
    xconv_kernel<<<dim3(2048), 256, 0, stream>>>(x, Xb, n4);
    lora_gemm_bf16<<<dim3(6, 64, 4), 256, 0, stream>>>(Xb, Weff, bp, out);
  } else {
    lora_gemm_fp32x<<<dim3(6, 64, 4), 256, 0, stream>>>(x, Weff, bp, out);
  }
}

// Round 3
// 270.731 us; speedup vs baseline: 1.0778x; 1.0778x over previous
//
#include <hip/hip_runtime.h>
#include <hip/hip_bf16.h>
#include <stdint.h>

#define NUM_MODALS 4
#define SHARED_IDX 3

typedef __attribute__((ext_vector_type(8))) short bf16x8;
typedef __attribute__((ext_vector_type(4))) float floatx4;

__device__ __forceinline__ unsigned short f2bf(float f) {
  unsigned int u = __float_as_uint(f);
  u += 0x7fffu + ((u >> 16) & 1u);   // round-to-nearest-even
  return (unsigned short)(u >> 16);
}

// ---------------- fused prep: X fp32->bf16 convert  +  W_eff build ----------------
// blocks [0, 2048): xconv  — grid-stride float4 convert of X (100 MB -> 50 MB)
// blocks [2048, 2048+192): weff — W_eff[m][o][c] = Wp[o][c]
//                                 + sum_r Bw[3][o][r]*A[3][r][c] + sum_r Bw[m][o][r]*A[m][r][c]
//   weff decomposition: bid -> (c_chunk 0..2, m 0..3, o_chunk 0..15), 48 o-rows/block.
//   Thread owns column c: A[.][c] in 32 regs (reused 48x), Bw reads wave-uniform (s_load),
//   2-way ILP over o to break the FMA dependence chain.
#define XCONV_BLOCKS 2048
#define WEFF_BLOCKS  192

__global__ __launch_bounds__(256) void prep_kernel(
    const float* __restrict__ X, unsigned short* __restrict__ Xb, int n4,
    const float* __restrict__ Wp, const float* __restrict__ A,
    const float* __restrict__ Bw, unsigned short* __restrict__ Weff) {
  if (blockIdx.x < XCONV_BLOCKS) {
    int idx = blockIdx.x * 256 + threadIdx.x;
    const int stride = XCONV_BLOCKS * 256;
    for (; idx < n4; idx += stride) {
      const float4 v = *(const float4*)(X + (size_t)idx * 4);
      ushort4 h;
      h.x = f2bf(v.x); h.y = f2bf(v.y); h.z = f2bf(v.z); h.w = f2bf(v.w);
      *(ushort4*)(Xb + (size_t)idx * 4) = h;
    }
  } else {
    const int bid = blockIdx.x - XCONV_BLOCKS;
    const int c  = (bid % 3) * 256 + threadIdx.x;
    const int m  = (bid / 3) % 4;
    const int o0 = (bid / 12) * 48;
    float a3[16], am[16];
#pragma unroll
    for (int r = 0; r < 16; ++r) {
      a3[r] = A[(SHARED_IDX * 16 + r) * 768 + c];
      am[r] = A[(m * 16 + r) * 768 + c];
    }
    for (int oo = 0; oo < 48; oo += 2) {
      const int o = o0 + oo;
      float acc0 = Wp[(size_t)o * 768 + c];
      float acc1 = Wp[(size_t)(o + 1) * 768 + c];
#pragma unroll
      for (int r = 0; r < 16; ++r) {
        acc0 += Bw[(SHARED_IDX * 768 + o) * 16 + r] * a3[r];
        acc1 += Bw[(SHARED_IDX * 768 + o + 1) * 16 + r] * a3[r];
        acc0 += Bw[(m * 768 + o) * 16 + r] * am[r];
        acc1 += Bw[(m * 768 + o + 1) * 16 + r] * am[r];
      }
      Weff[((size_t)m * 768 + o) * 768 + c]     = f2bf(acc0);
      Weff[((size_t)m * 768 + o + 1) * 768 + c] = f2bf(acc1);
    }
  }
}

// ---------------- main GEMM: out[m] = Xb[m] (8192x768 bf16) * Weff[m]^T + bp ----------------
// (byte-identical to round 2: 128x128 tile, BK=64, global_load_lds width-16,
//  XOR-swizzled LDS: row r, col-block kblk lives at slot kblk ^ (r & 7) -> 0 bank conflicts)
__global__ __launch_bounds__(256) void lora_gemm_bf16(
    const unsigned short* __restrict__ Xb,
    const unsigned short* __restrict__ Weff,
    const float* __restrict__ bp,
    float* __restrict__ out) {
  const int m = blockIdx.z;
  const int row_base = blockIdx.y * 128;
  const int col_base = blockIdx.x * 128;

  __shared__ alignas(16) unsigned short As[128 * 64];
  __shared__ alignas(16) unsigned short Ws[128 * 64];

  const int tid  = threadIdx.x;
  const int wave = tid >> 6;
  const int lane = tid & 63;
  const int ln = lane & 15;
  const int qd = lane >> 4;
  const int wm = wave & 1;
  const int wn = wave >> 1;

  const unsigned short* Xm = Xb   + (size_t)m * 8192 * 768;
  const unsigned short* Wm = Weff + (size_t)m * 768 * 768;

  floatx4 acc[4][4];
#pragma unroll
  for (int i = 0; i < 4; ++i)
#pragma unroll
    for (int j = 0; j < 4; ++j)
      acc[i][j] = (floatx4)(0.0f);

  const int sr = lane >> 3;          // row-in-8 for this lane
  const int ss = lane & 7;           // LDS slot (col-block) this lane fills
  for (int kt = 0; kt < 12; ++kt) {
    const int k0 = kt * 64;

#pragma unroll
    for (int p = 0; p < 4; ++p) {
      const int r = wave * 32 + p * 8 + sr;
      const int g = ss ^ (r & 7);    // global col-block that belongs in slot ss
      const unsigned short* srcA = Xm + (size_t)(row_base + r) * 768 + k0 + g * 8;
      __builtin_amdgcn_global_load_lds(
          (const __attribute__((address_space(1))) void*)srcA,
          (__attribute__((address_space(3))) void*)&As[(wave * 32 + p * 8) * 64],
          16, 0, 0);
      const unsigned short* srcW = Wm + (size_t)(col_base + r) * 768 + k0 + g * 8;
      __builtin_amdgcn_global_load_lds(
          (const __attribute__((address_space(1))) void*)srcW,
          (__attribute__((address_space(3))) void*)&Ws[(wave * 32 + p * 8) * 64],
          16, 0, 0);
    }
    __syncthreads();

#pragma unroll
    for (int kk = 0; kk < 64; kk += 32) {
      const int kblk = (kk >> 3) + qd;           // 0..7
      const int slot = (kblk ^ (ln & 7)) * 8;    // row&7 == ln&7 for all frag rows
      bf16x8 a[4], b[4];
#pragma unroll
      for (int i = 0; i < 4; ++i)
        a[i] = *(const bf16x8*)(&As[(wm * 64 + i * 16 + ln) * 64 + slot]);
#pragma unroll
      for (int j = 0; j < 4; ++j)
        b[j] = *(const bf16x8*)(&Ws[(wn * 64 + j * 16 + ln) * 64 + slot]);
#pragma unroll
      for (int i = 0; i < 4; ++i)
#pragma unroll
        for (int j = 0; j < 4; ++j)
          acc[i][j] = __builtin_amdgcn_mfma_f32_16x16x32_bf16(a[i], b[j], acc[i][j], 0, 0, 0);
    }
    __syncthreads();
  }

  float* Om = out + (size_t)m * 8192 * 768;
#pragma unroll
  for (int j = 0; j < 4; ++j) {
    const int o = col_base + wn * 64 + j * 16 + ln;
    const float bias = bp[o];
#pragma unroll
    for (int i = 0; i < 4; ++i) {
      const int R = row_base + wm * 64 + i * 16 + qd * 4;
      float* dst = Om + (size_t)R * 768 + o;
#pragma unroll
      for (int v = 0; v < 4; ++v)
        dst[(size_t)v * 768] = acc[i][j][v] + bias;
    }
  }
}

// ---------------- fallback GEMM (fp32 X staging, from round 1) ----------------
__global__ __launch_bounds__(256) void lora_gemm_fp32x(
    const float* __restrict__ X,
    const unsigned short* __restrict__ Weff,
    const float* __restrict__ bp,
    float* __restrict__ out) {
  const int m = blockIdx.z;
  const int row_base = blockIdx.y * 128;
  const int col_base = blockIdx.x * 128;
  __shared__ alignas(16) unsigned short As[128 * 64];
  __shared__ alignas(16) unsigned short Ws[128 * 64];
  const int tid  = threadIdx.x;
  const int wave = tid >> 6;
  const int lane = tid & 63;
  const int ln = lane & 15;
  const int qd = lane >> 4;
  const int wm = wave & 1;
  const int wn = wave >> 1;
  const float*          Xm = X    + (size_t)m * 8192 * 768;
  const unsigned short* Wm = Weff + (size_t)m * 768 * 768;
  floatx4 acc[4][4];
#pragma unroll
  for (int i = 0; i < 4; ++i)
#pragma unroll
    for (int j = 0; j < 4; ++j)
      acc[i][j] = (floatx4)(0.0f);
  const int xr = tid >> 4;
  const int xc = (tid & 15) * 4;
  for (int kt = 0; kt < 12; ++kt) {
    const int k0 = kt * 64;
#pragma unroll
    for (int p = 0; p < 8; ++p) {
      const int r = xr + p * 16;
      const float4 v = *(const float4*)(Xm + (size_t)(row_base + r) * 768 + k0 + xc);
      ushort4 h;
      h.x = f2bf(v.x); h.y = f2bf(v.y); h.z = f2bf(v.z); h.w = f2bf(v.w);
      *(ushort4*)(&As[r * 64 + xc]) = h;
    }
#pragma unroll
    for (int p = 0; p < 4; ++p) {
      const unsigned short* src = Wm + (size_t)(col_base + wave * 32 + p * 8 + (lane >> 3)) * 768 + k0 + (lane & 7) * 8;
      __builtin_amdgcn_global_load_lds(
          (const __attribute__((address_space(1))) void*)src,
          (__attribute__((address_space(3))) void*)&Ws[(wave * 32 + p * 8) * 64],
          16, 0, 0);
    }
    __syncthreads();
#pragma unroll
    for (int kk = 0; kk < 64; kk += 32) {
      bf16x8 a[4], b[4];
#pragma unroll
      for (int i = 0; i < 4; ++i)
        a[i] = *(const bf16x8*)(&As[(wm * 64 + i * 16 + ln) * 64 + kk + qd * 8]);
#pragma unroll
      for (int j = 0; j < 4; ++j)
        b[j] = *(const bf16x8*)(&Ws[(wn * 64 + j * 16 + ln) * 64 + kk + qd * 8]);
#pragma unroll
      for (int i = 0; i < 4; ++i)
#pragma unroll
        for (int j = 0; j < 4; ++j)
          acc[i][j] = __builtin_amdgcn_mfma_f32_16x16x32_bf16(a[i], b[j], acc[i][j], 0, 0, 0);
    }
    __syncthreads();
  }
  float* Om = out + (size_t)m * 8192 * 768;
#pragma unroll
  for (int j = 0; j < 4; ++j) {
    const int o = col_base + wn * 64 + j * 16 + ln;
    const float bias = bp[o];
#pragma unroll
    for (int i = 0; i < 4; ++i) {
      const int R = row_base + wm * 64 + i * 16 + qd * 4;
      float* dst = Om + (size_t)R * 768 + o;
#pragma unroll
      for (int v = 0; v < 4; ++v)
        dst[(size_t)v * 768] = acc[i][j][v] + bias;
    }
  }
}

// fallback weff (round-1 style, used only if ws too small for Xb)
__global__ void weff_kernel(const float* __restrict__ Wp,
                            const float* __restrict__ A,
                            const float* __restrict__ Bw,
                            unsigned short* __restrict__ Weff) {
  const int o = blockIdx.x;
  const int m = blockIdx.y;
  __shared__ float bsh[32];
  const int t = threadIdx.x;
  if (t < 16)      bsh[t] = Bw[(SHARED_IDX * 768 + o) * 16 + t];
  else if (t < 32) bsh[t] = Bw[(m * 768 + o) * 16 + (t - 16)];
  __syncthreads();
  for (int c = t; c < 768; c += 256) {
    float acc = Wp[o * 768 + c];
#pragma unroll
    for (int r = 0; r < 16; ++r) {
      acc += bsh[r]      * A[(SHARED_IDX * 16 + r) * 768 + c];
      acc += bsh[16 + r] * A[(m * 16 + r) * 768 + c];
    }
    Weff[((size_t)m * 768 + o) * 768 + c] = f2bf(acc);
  }
}

extern "C" void kernel_launch(void* const* d_in, const int* in_sizes, int n_in,
                              void* d_out, int out_size, void* d_ws, size_t ws_size,
                              hipStream_t stream) {
  const float* x  = (const float*)d_in[0];   // [32, 1024, 768]
  const float* Wp = (const float*)d_in[1];   // [768, 768]
  const float* bp = (const float*)d_in[2];   // [768]
  const float* A  = (const float*)d_in[3];   // [4, 16, 768]
  const float* Bw = (const float*)d_in[4];   // [4, 768, 16]
  float* out = (float*)d_out;                // [32, 1024, 768]

  const size_t weff_bytes = (size_t)NUM_MODALS * 768 * 768 * 2;      // 4.5 MB
  const size_t xb_bytes   = (size_t)NUM_MODALS * 8192 * 768 * 2;     // 50.3 MB

  unsigned short* Weff = (unsigned short*)d_ws;

  if (ws_size >= weff_bytes + xb_bytes) {
    unsigned short* Xb = (unsigned short*)((char*)d_ws + weff_bytes);
    const int n4 = NUM_MODALS * 8192 * 768 / 4;  // 6,291,456 float4 groups
    prep_kernel<<<dim3(XCONV_BLOCKS + WEFF_BLOCKS), 256, 0, stream>>>(
        x, Xb, n4, Wp, A, Bw, Weff);
    lora_gemm_bf16<<<dim3(6, 64, 4), 256, 0, stream>>>(Xb, Weff, bp, out);
  } else {
    weff_kernel<<<dim3(768, 4), 256, 0, stream>>>(Wp, A, Bw, Weff);
    lora_gemm_fp32x<<<dim3(6, 64, 4), 256, 0, stream>>>(x, Weff, bp, out);
  }
}

// Round 4
// 242.000 us; speedup vs baseline: 1.2058x; 1.1187x over previous
//
#include <hip/hip_runtime.h>
#include <hip/hip_bf16.h>
#include <stdint.h>

#define NUM_MODALS 4
#define SHARED_IDX 3

typedef __attribute__((ext_vector_type(8))) short bf16x8;
typedef __attribute__((ext_vector_type(4))) float floatx4;

__device__ __forceinline__ unsigned short f2bf(float f) {
  unsigned int u = __float_as_uint(f);
  u += 0x7fffu + ((u >> 16) & 1u);   // round-to-nearest-even
  return (unsigned short)(u >> 16);
}

// ---------------- W_eff build (latency-fixed) ----------------
// W_eff[m][o][c] = Wp[o][c] + sum_r Bw[3][o][r]*A[3][r][c] + sum_r Bw[m][o][r]*A[m][r][c]
// grid (3 c-chunks, 48 o-chunks, 4 m), block 256. Bw rows staged in LDS (one load
// per thread, broadcast reads in the FMA loop) -> no global-latency chain.
__global__ __launch_bounds__(256) void weff_fast(
    const float* __restrict__ Wp, const float* __restrict__ A,
    const float* __restrict__ Bw, unsigned short* __restrict__ Weff) {
  const int c  = blockIdx.x * 256 + threadIdx.x;
  const int o0 = blockIdx.y * 16;
  const int m  = blockIdx.z;

  __shared__ float b3[256], bm[256];   // 16 o-rows x 16 r, both adapters
  const int t = threadIdx.x;
  {
    const int o = o0 + (t >> 4);
    const int r = t & 15;
    b3[t] = Bw[(SHARED_IDX * 768 + o) * 16 + r];
    bm[t] = Bw[((size_t)m * 768 + o) * 16 + r];
  }
  __syncthreads();

  float a3[16], am[16];
#pragma unroll
  for (int r = 0; r < 16; ++r) {
    a3[r] = A[(SHARED_IDX * 16 + r) * 768 + c];
    am[r] = A[((size_t)m * 16 + r) * 768 + c];
  }
#pragma unroll 4
  for (int oo = 0; oo < 16; ++oo) {
    const int o = o0 + oo;
    float acc = Wp[(size_t)o * 768 + c];
#pragma unroll
    for (int r = 0; r < 16; ++r) {
      acc += b3[oo * 16 + r] * a3[r];
      acc += bm[oo * 16 + r] * am[r];
    }
    Weff[((size_t)m * 768 + o) * 768 + c] = f2bf(acc);
  }
}

// ---------------- fused GEMM: out[m] = X[m] (fp32, cvt in-reg) * Weff[m]^T + bp ----
// 128x128 tile, BK=64, 4 waves x 4x4 16x16x32-bf16 frags.
// X: float4 global loads -> v_cvt_pk_bf16_f32 -> XOR-swizzled LDS writes.
// W: global_load_lds width-16, same XOR swizzle (slot = colblk ^ (row&7)) -> 0 conflicts.
// XCD-aware remap: flat bid, xcd = bid&7 (round-robin dispatch assumption; perf-only):
// each XCD gets 192 consecutive work items where the 6 col-tiles of a row-tile are
// adjacent -> X row-tile fetched into that XCD's L2 once; one modality's W per XCD.
__global__ __launch_bounds__(256) void lora_gemm_fused(
    const float* __restrict__ X,
    const unsigned short* __restrict__ Weff,
    const float* __restrict__ bp,
    float* __restrict__ out) {
  const int bid = blockIdx.x;
  const int xcd = bid & 7;
  const int s   = bid >> 3;          // 0..191
  const int w   = xcd * 192 + s;     // contiguous per-XCD chunk
  const int ct  = w % 6;
  const int rt  = w / 6;             // 0..255
  const int m        = rt >> 6;
  const int row_base = (rt & 63) * 128;
  const int col_base = ct * 128;

  __shared__ alignas(16) unsigned short As[128 * 64];
  __shared__ alignas(16) unsigned short Ws[128 * 64];

  const int tid  = threadIdx.x;
  const int wave = tid >> 6;
  const int lane = tid & 63;
  const int ln = lane & 15;
  const int qd = lane >> 4;
  const int wm = wave & 1;
  const int wn = wave >> 1;

  const float*          Xm = X    + (size_t)m * 8192 * 768;
  const unsigned short* Wm = Weff + (size_t)m * 768 * 768;

  floatx4 acc[4][4];
#pragma unroll
  for (int i = 0; i < 4; ++i)
#pragma unroll
    for (int j = 0; j < 4; ++j)
      acc[i][j] = (floatx4)(0.0f);

  // --- X staging geometry: thread covers (row xr+p*16, 4 fp32 cols at xc) ---
  const int xr   = tid >> 4;         // 0..15
  const int xc   = (tid & 15) * 4;   // 0..60
  const int cb   = xc >> 3;          // 16B col-block 0..7
  const int half = (xc >> 2) & 1;    // which 8B half of the block
  // LDS dst is kt-invariant; global src advances by 64 per kt
  const float* xsrc[8];
  unsigned short* xdst[8];
#pragma unroll
  for (int p = 0; p < 8; ++p) {
    const int r = xr + p * 16;
    xsrc[p] = Xm + (size_t)(row_base + r) * 768 + xc;
    xdst[p] = &As[r * 64 + (cb ^ (r & 7)) * 8 + half * 4];
  }
  // --- W staging geometry (global_load_lds: 8 rows x 128 B per issue) ---
  const int sr = lane >> 3;          // row-in-8
  const int ss = lane & 7;           // LDS slot this lane fills
  const unsigned short* wsrc[4];
#pragma unroll
  for (int p = 0; p < 4; ++p) {
    const int r = wave * 32 + p * 8 + sr;
    wsrc[p] = Wm + (size_t)(col_base + r) * 768 + (ss ^ (r & 7)) * 8;
  }

  for (int kt = 0; kt < 12; ++kt) {
#pragma unroll
    for (int p = 0; p < 4; ++p) {
      __builtin_amdgcn_global_load_lds(
          (const __attribute__((address_space(1))) void*)wsrc[p],
          (__attribute__((address_space(3))) void*)&Ws[(wave * 32 + p * 8) * 64],
          16, 0, 0);
      wsrc[p] += 64;
    }
#pragma unroll
    for (int p = 0; p < 8; ++p) {
      const float4 v = *(const float4*)xsrc[p];
      xsrc[p] += 64;
      __hip_bfloat162 h0 = __float22bfloat162_rn(make_float2(v.x, v.y));
      __hip_bfloat162 h1 = __float22bfloat162_rn(make_float2(v.z, v.w));
      uint2 hv;
      hv.x = *(unsigned int*)&h0;
      hv.y = *(unsigned int*)&h1;
      *(uint2*)xdst[p] = hv;
    }
    __syncthreads();

#pragma unroll
    for (int kk = 0; kk < 64; kk += 32) {
      const int kblk = (kk >> 3) + qd;           // 0..7
      const int slot = (kblk ^ (ln & 7)) * 8;
      bf16x8 a[4], b[4];
#pragma unroll
      for (int i = 0; i < 4; ++i)
        a[i] = *(const bf16x8*)(&As[(wm * 64 + i * 16 + ln) * 64 + slot]);
#pragma unroll
      for (int j = 0; j < 4; ++j)
        b[j] = *(const bf16x8*)(&Ws[(wn * 64 + j * 16 + ln) * 64 + slot]);
#pragma unroll
      for (int i = 0; i < 4; ++i)
#pragma unroll
        for (int j = 0; j < 4; ++j)
          acc[i][j] = __builtin_amdgcn_mfma_f32_16x16x32_bf16(a[i], b[j], acc[i][j], 0, 0, 0);
    }
    __syncthreads();
  }

  float* Om = out + (size_t)m * 8192 * 768;
#pragma unroll
  for (int j = 0; j < 4; ++j) {
    const int o = col_base + wn * 64 + j * 16 + ln;
    const float bias = bp[o];
#pragma unroll
    for (int i = 0; i < 4; ++i) {
      const int R = row_base + wm * 64 + i * 16 + qd * 4;
      float* dst = Om + (size_t)R * 768 + o;
#pragma unroll
      for (int v = 0; v < 4; ++v)
        dst[(size_t)v * 768] = acc[i][j][v] + bias;
    }
  }
}

extern "C" void kernel_launch(void* const* d_in, const int* in_sizes, int n_in,
                              void* d_out, int out_size, void* d_ws, size_t ws_size,
                              hipStream_t stream) {
  const float* x  = (const float*)d_in[0];   // [32, 1024, 768]
  const float* Wp = (const float*)d_in[1];   // [768, 768]
  const float* bp = (const float*)d_in[2];   // [768]
  const float* A  = (const float*)d_in[3];   // [4, 16, 768]
  const float* Bw = (const float*)d_in[4];   // [4, 768, 16]
  float* out = (float*)d_out;                // [32, 1024, 768]

  unsigned short* Weff = (unsigned short*)d_ws;  // [4][768][768] bf16 = 4.5 MB

  weff_fast<<<dim3(3, 48, 4), 256, 0, stream>>>(Wp, A, Bw, Weff);
  lora_gemm_fused<<<dim3(1536), 256, 0, stream>>>(x, Weff, bp, out);
}